// Round 1
// baseline (1512.884 us; speedup 1.0000x reference)
//
#include <hip/hip_runtime.h>
#include <stdint.h>

// InteractionModel: N=8192, D=512, T=12. All inputs/outputs fp32.
// Strategy: LN -> bf16; 4x (Qproj GEMM, S=exp(QK^T-48) GEMM -> P bf16,
// PV GEMM with on-the-fly row-sum l via ones-MFMA -> F = softmax@V/sqrt(D));
// head kernel fuses concat+relu+Wp+gate.
// Workspace layout (bytes): needs 224 MB.
//   0M x1b, 8M x2b, 16M x4b          bf16 LN outputs [8192][512]
//  24M x1t, 32M x2t, 40M x4t         bf16 transposed [512][8192]
//  48M Wb (4x512x512 bf16)           56M Qb (bf16, reused)
//  64M P  (8192x8192 bf16, reused)  192M F1, 200M F2, 208M F3, 216M F4

#define DEV __device__ __forceinline__
typedef unsigned short u16;
typedef __bf16 bf16x8 __attribute__((ext_vector_type(8)));
typedef float f32x4 __attribute__((ext_vector_type(4)));

constexpr int NR = 8192;   // rows
constexpr int DDIM = 512;  // feature dim
constexpr int TOUT = 12;   // output dim

DEV u16 f2b(float f) {
  uint32_t u = __builtin_bit_cast(uint32_t, f);
  u += 0x7fffu + ((u >> 16) & 1u);
  return (u16)(u >> 16);
}
DEV float b2f(u16 h) {
  uint32_t u = ((uint32_t)h) << 16;
  return __builtin_bit_cast(float, u);
}

// ---------------- LayerNorm: fp32 in -> bf16 out ----------------
__global__ __launch_bounds__(64) void ln_kernel(
    const float* __restrict__ xp, const float* __restrict__ xm,
    const float* __restrict__ xs, const float* __restrict__ g,
    const float* __restrict__ b, u16* __restrict__ o1, u16* __restrict__ o2,
    u16* __restrict__ o4) {
  int row = blockIdx.x;
  int which = blockIdx.y;
  const float* x = which == 0 ? xp : (which == 1 ? xm : xs);
  u16* o = which == 0 ? o1 : (which == 1 ? o2 : o4);
  int lane = threadIdx.x;
  const float4* xr = (const float4*)(x + (size_t)row * DDIM);
  float4 v0 = xr[lane * 2], v1 = xr[lane * 2 + 1];
  float vals[8] = {v0.x, v0.y, v0.z, v0.w, v1.x, v1.y, v1.z, v1.w};
  float s = 0.f, s2 = 0.f;
  for (int j = 0; j < 8; j++) { s += vals[j]; s2 += vals[j] * vals[j]; }
  for (int off = 1; off < 64; off <<= 1) {
    s += __shfl_xor(s, off);
    s2 += __shfl_xor(s2, off);
  }
  float m = s * (1.0f / DDIM);
  float var = s2 * (1.0f / DDIM) - m * m;
  var = fmaxf(var, 0.f);
  float rs = rsqrtf(var + 1e-6f);
  int d0 = lane * 8;
  u16 us[8];
  for (int j = 0; j < 8; j++)
    us[j] = f2b((vals[j] - m) * rs * g[d0 + j] + b[d0 + j]);
  uint4 pk;
  pk.x = (uint32_t)us[0] | ((uint32_t)us[1] << 16);
  pk.y = (uint32_t)us[2] | ((uint32_t)us[3] << 16);
  pk.z = (uint32_t)us[4] | ((uint32_t)us[5] << 16);
  pk.w = (uint32_t)us[6] | ((uint32_t)us[7] << 16);
  *(uint4*)(o + (size_t)row * DDIM + d0) = pk;
}

// ---------------- W fp32 -> bf16 ----------------
__global__ __launch_bounds__(256) void wconv_kernel(
    const float* __restrict__ W1, const float* __restrict__ W2,
    const float* __restrict__ W3, const float* __restrict__ W4,
    u16* __restrict__ Wb) {
  int wi = blockIdx.y;
  const float* W = wi == 0 ? W1 : (wi == 1 ? W2 : (wi == 2 ? W3 : W4));
  size_t base = ((size_t)blockIdx.x * 256 + threadIdx.x) * 8;
  const float4* src = (const float4*)(W + base);
  float4 a = src[0], c = src[1];
  float vals[8] = {a.x, a.y, a.z, a.w, c.x, c.y, c.z, c.w};
  u16 us[8];
  for (int j = 0; j < 8; j++) us[j] = f2b(vals[j]);
  uint4 pk;
  pk.x = (uint32_t)us[0] | ((uint32_t)us[1] << 16);
  pk.y = (uint32_t)us[2] | ((uint32_t)us[3] << 16);
  pk.z = (uint32_t)us[4] | ((uint32_t)us[5] << 16);
  pk.w = (uint32_t)us[6] | ((uint32_t)us[7] << 16);
  *(uint4*)(Wb + (size_t)wi * DDIM * DDIM + base) = pk;
}

// ---------------- bf16 transpose [8192][512] -> [512][8192] ----------------
__global__ __launch_bounds__(256) void transpose_kernel(
    const u16* __restrict__ s1, const u16* __restrict__ s2,
    const u16* __restrict__ s4, u16* __restrict__ t1, u16* __restrict__ t2,
    u16* __restrict__ t4) {
  constexpr int LD = 66;
  __shared__ u16 tile[64 * LD];
  int which = blockIdx.z;
  const u16* src = which == 0 ? s1 : (which == 1 ? s2 : s4);
  u16* dst = which == 0 ? t1 : (which == 1 ? t2 : t4);
  int c0 = blockIdx.x * 64;  // feature-dim block
  int r0 = blockIdx.y * 64;  // row block
  int tid = threadIdx.x;
  for (int c = tid; c < 512; c += 256) {
    int i = c >> 3, j8 = (c & 7) * 8;
    uint4 v = *(const uint4*)(src + (size_t)(r0 + i) * DDIM + c0 + j8);
    uint32_t* dw = (uint32_t*)&tile[i * LD + j8];
    dw[0] = v.x; dw[1] = v.y; dw[2] = v.z; dw[3] = v.w;
  }
  __syncthreads();
  for (int c = tid; c < 512; c += 256) {
    int o = c >> 3, e8 = (c & 7) * 8;
    u16 us[8];
    for (int k = 0; k < 8; k++) us[k] = tile[(e8 + k) * LD + o];
    uint4 pk;
    pk.x = (uint32_t)us[0] | ((uint32_t)us[1] << 16);
    pk.y = (uint32_t)us[2] | ((uint32_t)us[3] << 16);
    pk.z = (uint32_t)us[4] | ((uint32_t)us[5] << 16);
    pk.w = (uint32_t)us[6] | ((uint32_t)us[7] << 16);
    *(uint4*)(dst + (size_t)(c0 + o) * NR + r0 + e8) = pk;
  }
}

// ---------------- generic bt-GEMM: C = A[M,K] * B[N,K]^T + epilogue --------
// MODE 0: out bf16 = acc + bias[col]          (Q projection)
// MODE 1: out bf16 = exp(acc - 48)            (scores -> P)
// MODE 2: out bf16 = acc / (l_row * sqrt(512)) (PV, l via ones-MFMA)
template <int MODE, int BM, int BN>
__global__ __launch_bounds__(256, 2) void gemm_bt(
    const u16* __restrict__ A, const u16* __restrict__ B,
    u16* __restrict__ C, const float* __restrict__ bias, int M, int Nn, int K,
    int lda, int ldb, int ldc) {
  constexpr int TM = BM / 32, TN = BN / 32;
  __shared__ u16 Asm[BM * 32];
  __shared__ u16 Bsm[BN * 32];
  int tid = threadIdx.x;
  int w = tid >> 6, lane = tid & 63;
  int q = lane >> 4, c16 = lane & 15;
  int n0 = blockIdx.x * BN, m0 = blockIdx.y * BM;
  int wrow = (w >> 1) * (BM / 2), wcol = (w & 1) * (BN / 2);
  f32x4 acc[TM][TN] = {};
  f32x4 accl[TM];
  bf16x8 ones;
  if constexpr (MODE == 2) {
    for (int i = 0; i < TM; i++) accl[i] = f32x4{0.f, 0.f, 0.f, 0.f};
    for (int j = 0; j < 8; j++) ones[j] = (__bf16)1.0f;
  }
  constexpr int ACALLS = BM / 16, BCALLS = BN / 16;
  for (int k0 = 0; k0 < K; k0 += 32) {
    __syncthreads();  // previous iter's reads done before overwrite
    for (int call = w; call < ACALLS + BCALLS; call += 4) {
      bool isA = call < ACALLS;
      int ci = isA ? call : call - ACALLS;
      int chunk = ci * 64 + lane;
      const u16* gp = isA ? (A + (size_t)(m0 + (chunk >> 2)) * lda + k0 + (chunk & 3) * 8)
                          : (B + (size_t)(n0 + (chunk >> 2)) * ldb + k0 + (chunk & 3) * 8);
      u16* lp = (isA ? Asm : Bsm) + ci * 512;  // wave-uniform base; HW adds lane*16
      __builtin_amdgcn_global_load_lds(
          (const __attribute__((address_space(1))) void*)gp,
          (__attribute__((address_space(3))) void*)lp, 16, 0, 0);
    }
    __syncthreads();  // vmcnt(0) drained by compiler before barrier
    bf16x8 af[TM], bfr[TN];
    for (int i = 0; i < TM; i++)
      af[i] = *(const bf16x8*)&Asm[(wrow + i * 16 + c16) * 32 + q * 8];
    for (int n = 0; n < TN; n++)
      bfr[n] = *(const bf16x8*)&Bsm[(wcol + n * 16 + c16) * 32 + q * 8];
    if constexpr (MODE == 2)
      for (int i = 0; i < TM; i++)
        accl[i] = __builtin_amdgcn_mfma_f32_16x16x32_bf16(af[i], ones, accl[i], 0, 0, 0);
    for (int i = 0; i < TM; i++)
      for (int n = 0; n < TN; n++)
        acc[i][n] = __builtin_amdgcn_mfma_f32_16x16x32_bf16(af[i], bfr[n], acc[i][n], 0, 0, 0);
  }
  // epilogue
  for (int i = 0; i < TM; i++) {
    float invl[4];
    if constexpr (MODE == 2)
      for (int r = 0; r < 4; r++)
        invl[r] = 0.044194173824159216f / accl[i][r];  // 1/(l*sqrt(512))
    for (int n = 0; n < TN; n++) {
      int col = n0 + wcol + n * 16 + c16;
      float bv = 0.f;
      if constexpr (MODE == 0) bv = bias[col];
      for (int r = 0; r < 4; r++) {
        int row = m0 + wrow + i * 16 + q * 4 + r;
        float v = acc[i][n][r];
        if constexpr (MODE == 0) v += bv;
        if constexpr (MODE == 1) v = __expf(v - 48.0f);
        if constexpr (MODE == 2) v *= invl[r];
        C[(size_t)row * ldc + col] = f2b(v);
      }
    }
  }
}

// ---------------- fused head: concat+relu+Wp+bias+gate ----------------
__global__ __launch_bounds__(256) void head_kernel(
    const u16* __restrict__ F1, const u16* __restrict__ F2,
    const u16* __restrict__ F3, const u16* __restrict__ F4,
    const u16* __restrict__ x1, const u16* __restrict__ x2,
    const u16* __restrict__ x4, const float* __restrict__ Wp,
    const float* __restrict__ bp, const float* __restrict__ tg,
    const float* __restrict__ Wt1, const float* __restrict__ bt1,
    const float* __restrict__ Wt2, const float* __restrict__ bt2,
    float* __restrict__ out) {
  __shared__ float wps[TOUT * 2 * DDIM];  // 48 KB
  __shared__ float t2s;
  int tid = threadIdx.x;
  for (int i = tid; i < TOUT * 2 * DDIM; i += 256) wps[i] = Wp[i];
  if (tid == 0) {
    float s = bt2[0];
    for (int k = 0; k < 50; k++) s += Wt2[k] * (tg[0] * Wt1[k] + bt1[k]);
    t2s = 1.0f / (1.0f + __expf(-s));
  }
  __syncthreads();
  int g = tid >> 5, j = tid & 31;
  size_t m = (size_t)blockIdx.x * 8 + g;
  float a12[TOUT] = {}, a34[TOUT] = {};
  for (int d = j; d < 2 * DDIM; d += 32) {
    float h12, h34;
    if (d < DDIM) {
      float xv = b2f(x1[m * DDIM + d]);
      h12 = b2f(F1[m * DDIM + d]) + xv;
      h34 = b2f(F3[m * DDIM + d]) + xv;  // x3 == x1
    } else {
      int dd = d - DDIM;
      h12 = b2f(F2[m * DDIM + dd]) + b2f(x2[m * DDIM + dd]);
      h34 = b2f(F4[m * DDIM + dd]) + b2f(x4[m * DDIM + dd]);
    }
    h12 = fmaxf(h12, 0.f);
    h34 = fmaxf(h34, 0.f);
    for (int t = 0; t < TOUT; t++) {
      float wv = wps[t * 2 * DDIM + d];
      a12[t] += h12 * wv;
      a34[t] += h34 * wv;
    }
  }
  for (int off = 1; off < 32; off <<= 1)
    for (int t = 0; t < TOUT; t++) {
      a12[t] += __shfl_xor(a12[t], off);
      a34[t] += __shfl_xor(a34[t], off);
    }
  if (j < TOUT) {
    float t2 = t2s;
    out[m * TOUT + j] = t2 * a12[j] + (1.f - t2) * a34[j] + bp[j];
  }
}

extern "C" void kernel_launch(void* const* d_in, const int* in_sizes, int n_in,
                              void* d_out, int out_size, void* d_ws,
                              size_t ws_size, hipStream_t stream) {
  (void)in_sizes; (void)n_in; (void)out_size; (void)ws_size;
  const float* xp = (const float*)d_in[0];
  const float* xm = (const float*)d_in[1];
  const float* xs = (const float*)d_in[2];
  const float* ln_g = (const float*)d_in[3];
  const float* ln_b = (const float*)d_in[4];
  const float* Wmat[4] = {(const float*)d_in[5], (const float*)d_in[7],
                          (const float*)d_in[9], (const float*)d_in[11]};
  const float* bvec[4] = {(const float*)d_in[6], (const float*)d_in[8],
                          (const float*)d_in[10], (const float*)d_in[12]};
  const float* Wp = (const float*)d_in[13];
  const float* bp = (const float*)d_in[14];
  const float* tg = (const float*)d_in[15];
  const float* Wt1 = (const float*)d_in[16];
  const float* bt1 = (const float*)d_in[17];
  const float* Wt2 = (const float*)d_in[18];
  const float* bt2 = (const float*)d_in[19];
  float* out = (float*)d_out;

  char* ws = (char*)d_ws;
  const size_t MB = 1ull << 20;
  u16* x1b = (u16*)(ws + 0 * MB);
  u16* x2b = (u16*)(ws + 8 * MB);
  u16* x4b = (u16*)(ws + 16 * MB);
  u16* x1t = (u16*)(ws + 24 * MB);
  u16* x2t = (u16*)(ws + 32 * MB);
  u16* x4t = (u16*)(ws + 40 * MB);
  u16* Wb = (u16*)(ws + 48 * MB);
  u16* Qb = (u16*)(ws + 56 * MB);
  u16* P = (u16*)(ws + 64 * MB);
  u16* Fb[4] = {(u16*)(ws + 192 * MB), (u16*)(ws + 200 * MB),
                (u16*)(ws + 208 * MB), (u16*)(ws + 216 * MB)};  // f1,f2,f3,f4

  ln_kernel<<<dim3(NR, 3), 64, 0, stream>>>(xp, xm, xs, ln_g, ln_b, x1b, x2b, x4b);
  wconv_kernel<<<dim3(128, 4), 256, 0, stream>>>(Wmat[0], Wmat[1], Wmat[2], Wmat[3], Wb);
  transpose_kernel<<<dim3(8, 128, 3), 256, 0, stream>>>(x1b, x2b, x4b, x1t, x2t, x4t);

  // attention a: Q = LN(src)W_a^T + b_a  over  KV; writes F[fidx]
  const u16* qsrc[4] = {x1b, x2b, x1b, x4b};
  const u16* kvb[4] = {x2b, x1b, x4b, x1b};
  const u16* kvt[4] = {x2t, x1t, x4t, x1t};
  const int fidx[4] = {1, 0, 3, 2};  // a0->f2, a1->f1, a2->f4, a3->f3

  for (int a = 0; a < 4; a++) {
    // Q projection: [8192,512] x [512,512]^T
    gemm_bt<0, 64, 64><<<dim3(DDIM / 64, NR / 64), 256, 0, stream>>>(
        qsrc[a], Wb + (size_t)a * DDIM * DDIM, Qb, bvec[a], NR, DDIM, DDIM,
        DDIM, DDIM, DDIM);
    // scores: P = exp(Q K^T - 48), [8192,8192]
    gemm_bt<1, 128, 128><<<dim3(NR / 128, NR / 128), 256, 0, stream>>>(
        Qb, kvb[a], P, nullptr, NR, NR, DDIM, DDIM, DDIM, NR);
    // PV: F = (P V)/(l sqrt(512)), [8192,512], K=8192, B = V^T (pre-transposed)
    gemm_bt<2, 128, 64><<<dim3(DDIM / 64, NR / 128), 256, 0, stream>>>(
        P, kvt[a], Fb[fidx[a]], nullptr, NR, DDIM, NR, NR, NR, DDIM);
  }

  head_kernel<<<dim3(NR / 8), 256, 0, stream>>>(
      Fb[0], Fb[1], Fb[2], Fb[3], x1b, x2b, x4b, Wp, bp, tg, Wt1, bt1, Wt2,
      bt2, out);
}

// Round 2
// 1424.319 us; speedup vs baseline: 1.0622x; 1.0622x over previous
//
#include <hip/hip_runtime.h>
#include <stdint.h>

// InteractionModel: N=8192, D=512, T=12. All inputs/outputs fp32.
// R1: PV retiled BM=64/BN=256 (P re-read 8x -> 2x), K64 staging rounds,
//     [64x64] wave tiles; Qproj batched z=4; F_a overlays Q_a slot.
// Workspace (<= 212 MB):
//   0M x1b, 8M x2b, 16M x4b        bf16 LN outputs [8192][512]
//  24M x1t, 32M x2t, 40M x4t       bf16 transposed [512][8192]
//  48M Wb (4x512x512 bf16, 2MB)
//  52M Q/F slots (4 x 8MB)         Q_a; PV_a overwrites with F_a
//  84M P (8192x8192 bf16, 128MB)

#define DEV __device__ __forceinline__
typedef unsigned short u16;
typedef __bf16 bf16x8 __attribute__((ext_vector_type(8)));
typedef float f32x4 __attribute__((ext_vector_type(4)));

constexpr int NR = 8192;
constexpr int DDIM = 512;
constexpr int TOUT = 12;

DEV u16 f2b(float f) {
  uint32_t u = __builtin_bit_cast(uint32_t, f);
  u += 0x7fffu + ((u >> 16) & 1u);
  return (u16)(u >> 16);
}
DEV float b2f(u16 h) {
  uint32_t u = ((uint32_t)h) << 16;
  return __builtin_bit_cast(float, u);
}

// ---------------- LayerNorm: fp32 in -> bf16 out ----------------
__global__ __launch_bounds__(64) void ln_kernel(
    const float* __restrict__ xp, const float* __restrict__ xm,
    const float* __restrict__ xs, const float* __restrict__ g,
    const float* __restrict__ b, u16* __restrict__ o1, u16* __restrict__ o2,
    u16* __restrict__ o4) {
  int row = blockIdx.x;
  int which = blockIdx.y;
  const float* x = which == 0 ? xp : (which == 1 ? xm : xs);
  u16* o = which == 0 ? o1 : (which == 1 ? o2 : o4);
  int lane = threadIdx.x;
  const float4* xr = (const float4*)(x + (size_t)row * DDIM);
  float4 v0 = xr[lane * 2], v1 = xr[lane * 2 + 1];
  float vals[8] = {v0.x, v0.y, v0.z, v0.w, v1.x, v1.y, v1.z, v1.w};
  float s = 0.f, s2 = 0.f;
  for (int j = 0; j < 8; j++) { s += vals[j]; s2 += vals[j] * vals[j]; }
  for (int off = 1; off < 64; off <<= 1) {
    s += __shfl_xor(s, off);
    s2 += __shfl_xor(s2, off);
  }
  float m = s * (1.0f / DDIM);
  float var = s2 * (1.0f / DDIM) - m * m;
  var = fmaxf(var, 0.f);
  float rs = rsqrtf(var + 1e-6f);
  int d0 = lane * 8;
  u16 us[8];
  for (int j = 0; j < 8; j++)
    us[j] = f2b((vals[j] - m) * rs * g[d0 + j] + b[d0 + j]);
  uint4 pk;
  pk.x = (uint32_t)us[0] | ((uint32_t)us[1] << 16);
  pk.y = (uint32_t)us[2] | ((uint32_t)us[3] << 16);
  pk.z = (uint32_t)us[4] | ((uint32_t)us[5] << 16);
  pk.w = (uint32_t)us[6] | ((uint32_t)us[7] << 16);
  *(uint4*)(o + (size_t)row * DDIM + d0) = pk;
}

// ---------------- W fp32 -> bf16 ----------------
__global__ __launch_bounds__(256) void wconv_kernel(
    const float* __restrict__ W1, const float* __restrict__ W2,
    const float* __restrict__ W3, const float* __restrict__ W4,
    u16* __restrict__ Wb) {
  int wi = blockIdx.y;
  const float* W = wi == 0 ? W1 : (wi == 1 ? W2 : (wi == 2 ? W3 : W4));
  size_t base = ((size_t)blockIdx.x * 256 + threadIdx.x) * 8;
  const float4* src = (const float4*)(W + base);
  float4 a = src[0], c = src[1];
  float vals[8] = {a.x, a.y, a.z, a.w, c.x, c.y, c.z, c.w};
  u16 us[8];
  for (int j = 0; j < 8; j++) us[j] = f2b(vals[j]);
  uint4 pk;
  pk.x = (uint32_t)us[0] | ((uint32_t)us[1] << 16);
  pk.y = (uint32_t)us[2] | ((uint32_t)us[3] << 16);
  pk.z = (uint32_t)us[4] | ((uint32_t)us[5] << 16);
  pk.w = (uint32_t)us[6] | ((uint32_t)us[7] << 16);
  *(uint4*)(Wb + (size_t)wi * DDIM * DDIM + base) = pk;
}

// ---------------- bf16 transpose [8192][512] -> [512][8192] ----------------
__global__ __launch_bounds__(256) void transpose_kernel(
    const u16* __restrict__ s1, const u16* __restrict__ s2,
    const u16* __restrict__ s4, u16* __restrict__ t1, u16* __restrict__ t2,
    u16* __restrict__ t4) {
  constexpr int LD = 66;
  __shared__ u16 tile[64 * LD];
  int which = blockIdx.z;
  const u16* src = which == 0 ? s1 : (which == 1 ? s2 : s4);
  u16* dst = which == 0 ? t1 : (which == 1 ? t2 : t4);
  int c0 = blockIdx.x * 64;
  int r0 = blockIdx.y * 64;
  int tid = threadIdx.x;
  for (int c = tid; c < 512; c += 256) {
    int i = c >> 3, j8 = (c & 7) * 8;
    uint4 v = *(const uint4*)(src + (size_t)(r0 + i) * DDIM + c0 + j8);
    uint32_t* dw = (uint32_t*)&tile[i * LD + j8];
    dw[0] = v.x; dw[1] = v.y; dw[2] = v.z; dw[3] = v.w;
  }
  __syncthreads();
  for (int c = tid; c < 512; c += 256) {
    int o = c >> 3, e8 = (c & 7) * 8;
    u16 us[8];
    for (int k = 0; k < 8; k++) us[k] = tile[(e8 + k) * LD + o];
    uint4 pk;
    pk.x = (uint32_t)us[0] | ((uint32_t)us[1] << 16);
    pk.y = (uint32_t)us[2] | ((uint32_t)us[3] << 16);
    pk.z = (uint32_t)us[4] | ((uint32_t)us[5] << 16);
    pk.w = (uint32_t)us[6] | ((uint32_t)us[7] << 16);
    *(uint4*)(dst + (size_t)(c0 + o) * NR + r0 + e8) = pk;
  }
}

// ---------------- shared bt-GEMM core (BM=BN=128, BK=32, 2x2 wave grid) ----
// MODE 0: out bf16 = acc + bias[col]   MODE 1: out bf16 = exp(acc - 48)
template <int MODE>
DEV void gemm_core(const u16* __restrict__ A, const u16* __restrict__ B,
                   u16* __restrict__ C, const float* __restrict__ bias, int K,
                   int lda, int ldb, int ldc, int bx, int by) {
  constexpr int BM = 128, BN = 128, TM = 4, TN = 4;
  __shared__ u16 Asm[BM * 32];
  __shared__ u16 Bsm[BN * 32];
  int tid = threadIdx.x;
  int w = tid >> 6, lane = tid & 63;
  int q = lane >> 4, c16 = lane & 15;
  int n0 = bx * BN, m0 = by * BM;
  int wrow = (w >> 1) * 64, wcol = (w & 1) * 64;
  f32x4 acc[TM][TN] = {};
  for (int k0 = 0; k0 < K; k0 += 32) {
    __syncthreads();
    for (int call = w; call < 16; call += 4) {
      bool isA = call < 8;
      int ci = isA ? call : call - 8;
      int chunk = ci * 64 + lane;
      const u16* gp = isA
          ? (A + (size_t)(m0 + (chunk >> 2)) * lda + k0 + (chunk & 3) * 8)
          : (B + (size_t)(n0 + (chunk >> 2)) * ldb + k0 + (chunk & 3) * 8);
      u16* lp = (isA ? Asm : Bsm) + ci * 512;  // wave-uniform base
      __builtin_amdgcn_global_load_lds(
          (const __attribute__((address_space(1))) void*)gp,
          (__attribute__((address_space(3))) void*)lp, 16, 0, 0);
    }
    __syncthreads();
    bf16x8 af[TM], bfr[TN];
    for (int i = 0; i < TM; i++)
      af[i] = *(const bf16x8*)&Asm[(wrow + i * 16 + c16) * 32 + q * 8];
    for (int n = 0; n < TN; n++)
      bfr[n] = *(const bf16x8*)&Bsm[(wcol + n * 16 + c16) * 32 + q * 8];
    for (int i = 0; i < TM; i++)
      for (int n = 0; n < TN; n++)
        acc[i][n] = __builtin_amdgcn_mfma_f32_16x16x32_bf16(af[i], bfr[n],
                                                            acc[i][n], 0, 0, 0);
  }
  for (int i = 0; i < TM; i++) {
    for (int n = 0; n < TN; n++) {
      int col = n0 + wcol + n * 16 + c16;
      float bv = 0.f;
      if constexpr (MODE == 0) bv = bias[col];
      for (int r = 0; r < 4; r++) {
        int row = m0 + wrow + i * 16 + q * 4 + r;
        float v = acc[i][n][r];
        if constexpr (MODE == 0) v += bv;
        if constexpr (MODE == 1) v = __expf(v - 48.0f);
        C[(size_t)row * ldc + col] = f2b(v);
      }
    }
  }
}

// scores: P = exp(Q K^T - 48)
__global__ __launch_bounds__(256, 2) void scores_kernel(
    const u16* __restrict__ Q, const u16* __restrict__ Kv,
    u16* __restrict__ P) {
  gemm_core<1>(Q, Kv, P, nullptr, DDIM, DDIM, DDIM, NR, blockIdx.x,
               blockIdx.y);
}

// qproj (z-batched): Q_z = X_z W_z^T + b_z
__global__ __launch_bounds__(256, 2) void qproj_kernel(
    const u16* __restrict__ s0, const u16* __restrict__ s1,
    const u16* __restrict__ s2, const u16* __restrict__ s3,
    const u16* __restrict__ Wb, const float* __restrict__ b0,
    const float* __restrict__ b1, const float* __restrict__ b2,
    const float* __restrict__ b3, u16* __restrict__ Qs) {
  int z = blockIdx.z;
  const u16* A = z == 0 ? s0 : (z == 1 ? s1 : (z == 2 ? s2 : s3));
  const float* bias = z == 0 ? b0 : (z == 1 ? b1 : (z == 2 ? b2 : b3));
  gemm_core<0>(A, Wb + (size_t)z * DDIM * DDIM,
               Qs + (size_t)z * NR * DDIM, bias, DDIM, DDIM, DDIM, DDIM,
               blockIdx.x, blockIdx.y);
}

// ---------------- PV: F = (P V) / (l sqrt(512)) ----------------
// BM=64, BN=256, BK=64, 4 waves in 1x4 grid ([64x64] tiles, TM=TN=4).
// grid (512/256, 8192/64) = (2,128) = 256 blocks. P re-read only 2x.
__global__ __launch_bounds__(256, 2) void pv_kernel(
    const u16* __restrict__ A,  // P [8192][8192]
    const u16* __restrict__ B,  // V^T [512][8192]
    u16* __restrict__ C) {      // F [8192][512]
  constexpr int BM = 64, BN = 256, BK = 64;
  __shared__ u16 Asm[BM * BK];  // 8 KB
  __shared__ u16 Bsm[BN * BK];  // 32 KB
  int tid = threadIdx.x, w = tid >> 6, lane = tid & 63;
  int q = lane >> 4, c16 = lane & 15;
  int n0 = blockIdx.x * BN, m0 = blockIdx.y * BM;
  int wcol = w * 64;
  f32x4 acc[4][4] = {};
  f32x4 accl[4];
  for (int i = 0; i < 4; i++) accl[i] = f32x4{0.f, 0.f, 0.f, 0.f};
  bf16x8 ones;
  for (int j = 0; j < 8; j++) ones[j] = (__bf16)1.0f;
  for (int k0 = 0; k0 < NR; k0 += BK) {
    __syncthreads();
    // stage A (512 chunks) + B (2048 chunks), 16B each, 10 rounds of 256 lanes
    for (int it = 0; it < 10; it++) {
      int cb = it * 256 + w * 64;  // wave-uniform
      int c = cb + lane;
      bool isA = cb < 512;  // uniform per wave per it (512 % 64 == 0)
      int ci = isA ? c : c - 512;
      int row = ci >> 3, koff = (ci & 7) * 8;
      const u16* gp = isA ? (A + (size_t)(m0 + row) * NR + k0 + koff)
                          : (B + (size_t)(n0 + row) * NR + k0 + koff);
      u16* lp = isA ? (Asm + (size_t)cb * 8) : (Bsm + (size_t)(cb - 512) * 8);
      __builtin_amdgcn_global_load_lds(
          (const __attribute__((address_space(1))) void*)gp,
          (__attribute__((address_space(3))) void*)lp, 16, 0, 0);
    }
    __syncthreads();
    for (int kh = 0; kh < 2; kh++) {
      bf16x8 af[4], bfr[4];
      for (int i = 0; i < 4; i++)
        af[i] = *(const bf16x8*)&Asm[(i * 16 + c16) * BK + kh * 32 + q * 8];
      for (int n = 0; n < 4; n++)
        bfr[n] =
            *(const bf16x8*)&Bsm[(wcol + n * 16 + c16) * BK + kh * 32 + q * 8];
      for (int i = 0; i < 4; i++)
        accl[i] =
            __builtin_amdgcn_mfma_f32_16x16x32_bf16(af[i], ones, accl[i], 0, 0, 0);
      for (int i = 0; i < 4; i++)
        for (int n = 0; n < 4; n++)
          acc[i][n] = __builtin_amdgcn_mfma_f32_16x16x32_bf16(af[i], bfr[n],
                                                              acc[i][n], 0, 0, 0);
    }
  }
  for (int i = 0; i < 4; i++) {
    float invl[4];
    for (int r = 0; r < 4; r++)
      invl[r] = 0.044194173824159216f / accl[i][r];  // 1/(l*sqrt(512))
    for (int n = 0; n < 4; n++) {
      int col = n0 + wcol + n * 16 + c16;
      for (int r = 0; r < 4; r++) {
        int row = m0 + i * 16 + q * 4 + r;
        C[(size_t)row * DDIM + col] = f2b(acc[i][n][r] * invl[r]);
      }
    }
  }
}

// ---------------- fused head: concat+relu+Wp+bias+gate ----------------
__global__ __launch_bounds__(256) void head_kernel(
    const u16* __restrict__ F1, const u16* __restrict__ F2,
    const u16* __restrict__ F3, const u16* __restrict__ F4,
    const u16* __restrict__ x1, const u16* __restrict__ x2,
    const u16* __restrict__ x4, const float* __restrict__ Wp,
    const float* __restrict__ bp, const float* __restrict__ tg,
    const float* __restrict__ Wt1, const float* __restrict__ bt1,
    const float* __restrict__ Wt2, const float* __restrict__ bt2,
    float* __restrict__ out) {
  __shared__ float wps[TOUT * 2 * DDIM];
  __shared__ float t2s;
  int tid = threadIdx.x;
  for (int i = tid; i < TOUT * 2 * DDIM; i += 256) wps[i] = Wp[i];
  if (tid == 0) {
    float s = bt2[0];
    for (int k = 0; k < 50; k++) s += Wt2[k] * (tg[0] * Wt1[k] + bt1[k]);
    t2s = 1.0f / (1.0f + __expf(-s));
  }
  __syncthreads();
  int g = tid >> 5, j = tid & 31;
  size_t m = (size_t)blockIdx.x * 8 + g;
  float a12[TOUT] = {}, a34[TOUT] = {};
  for (int d = j; d < 2 * DDIM; d += 32) {
    float h12, h34;
    if (d < DDIM) {
      float xv = b2f(x1[m * DDIM + d]);
      h12 = b2f(F1[m * DDIM + d]) + xv;
      h34 = b2f(F3[m * DDIM + d]) + xv;
    } else {
      int dd = d - DDIM;
      h12 = b2f(F2[m * DDIM + dd]) + b2f(x2[m * DDIM + dd]);
      h34 = b2f(F4[m * DDIM + dd]) + b2f(x4[m * DDIM + dd]);
    }
    h12 = fmaxf(h12, 0.f);
    h34 = fmaxf(h34, 0.f);
    for (int t = 0; t < TOUT; t++) {
      float wv = wps[t * 2 * DDIM + d];
      a12[t] += h12 * wv;
      a34[t] += h34 * wv;
    }
  }
  for (int off = 1; off < 32; off <<= 1)
    for (int t = 0; t < TOUT; t++) {
      a12[t] += __shfl_xor(a12[t], off);
      a34[t] += __shfl_xor(a34[t], off);
    }
  if (j < TOUT) {
    float t2 = t2s;
    out[m * TOUT + j] = t2 * a12[j] + (1.f - t2) * a34[j] + bp[j];
  }
}

extern "C" void kernel_launch(void* const* d_in, const int* in_sizes, int n_in,
                              void* d_out, int out_size, void* d_ws,
                              size_t ws_size, hipStream_t stream) {
  (void)in_sizes; (void)n_in; (void)out_size; (void)ws_size;
  const float* xp = (const float*)d_in[0];
  const float* xm = (const float*)d_in[1];
  const float* xs = (const float*)d_in[2];
  const float* ln_g = (const float*)d_in[3];
  const float* ln_b = (const float*)d_in[4];
  const float* Wmat[4] = {(const float*)d_in[5], (const float*)d_in[7],
                          (const float*)d_in[9], (const float*)d_in[11]};
  const float* bvec[4] = {(const float*)d_in[6], (const float*)d_in[8],
                          (const float*)d_in[10], (const float*)d_in[12]};
  const float* Wp = (const float*)d_in[13];
  const float* bp = (const float*)d_in[14];
  const float* tg = (const float*)d_in[15];
  const float* Wt1 = (const float*)d_in[16];
  const float* bt1 = (const float*)d_in[17];
  const float* Wt2 = (const float*)d_in[18];
  const float* bt2 = (const float*)d_in[19];
  float* out = (float*)d_out;

  char* ws = (char*)d_ws;
  const size_t MB = 1ull << 20;
  u16* x1b = (u16*)(ws + 0 * MB);
  u16* x2b = (u16*)(ws + 8 * MB);
  u16* x4b = (u16*)(ws + 16 * MB);
  u16* x1t = (u16*)(ws + 24 * MB);
  u16* x2t = (u16*)(ws + 32 * MB);
  u16* x4t = (u16*)(ws + 40 * MB);
  u16* Wb = (u16*)(ws + 48 * MB);
  u16* Qs = (u16*)(ws + 52 * MB);  // 4 slots of 8 MB; F_a overlays Q_a
  u16* P = (u16*)(ws + 84 * MB);   // 128 MiB

  ln_kernel<<<dim3(NR, 3), 64, 0, stream>>>(xp, xm, xs, ln_g, ln_b, x1b, x2b,
                                            x4b);
  wconv_kernel<<<dim3(128, 4), 256, 0, stream>>>(Wmat[0], Wmat[1], Wmat[2],
                                                 Wmat[3], Wb);
  transpose_kernel<<<dim3(8, 128, 3), 256, 0, stream>>>(x1b, x2b, x4b, x1t,
                                                        x2t, x4t);
  // batched Q projections: z=0..3 -> slots 0..3
  qproj_kernel<<<dim3(DDIM / 128, NR / 128, 4), 256, 0, stream>>>(
      x1b, x2b, x1b, x4b, Wb, bvec[0], bvec[1], bvec[2], bvec[3], Qs);

  const u16* kvb[4] = {x2b, x1b, x4b, x1b};
  const u16* kvt[4] = {x2t, x1t, x4t, x1t};
  u16* slot[4];
  for (int a = 0; a < 4; a++) slot[a] = Qs + (size_t)a * NR * DDIM;

  for (int a = 0; a < 4; a++) {
    scores_kernel<<<dim3(NR / 128, NR / 128), 256, 0, stream>>>(slot[a],
                                                                kvb[a], P);
    // PV writes F_a over Q_a's slot (Q_a dead after scores_a)
    pv_kernel<<<dim3(DDIM / 256, NR / 64), 256, 0, stream>>>(P, kvt[a],
                                                             slot[a]);
  }

  // attention a -> f[fidx[a]]: a0->f2, a1->f1, a2->f4, a3->f3
  head_kernel<<<dim3(NR / 8), 256, 0, stream>>>(
      slot[1], slot[0], slot[3], slot[2], x1b, x2b, x4b, Wp, bp, tg, Wt1, bt1,
      Wt2, bt2, out);
}